// Round 4
// baseline (454.421 us; speedup 1.0000x reference)
//
#include <hip/hip_runtime.h>
#include <hip/hip_bf16.h>

typedef __attribute__((ext_vector_type(8))) short short8;
typedef __attribute__((ext_vector_type(4))) float f32x4;

#define GLD16(gp, lp) \
  __builtin_amdgcn_global_load_lds((const __attribute__((address_space(1))) void*)(gp), \
                                   (__attribute__((address_space(3))) void*)(lp), 16, 0, 0)

__device__ __forceinline__ f32x4 mfma_bf16(short8 a, short8 b, f32x4 c) {
  return __builtin_amdgcn_mfma_f32_16x16x32_bf16(a, b, c, 0, 0, 0);
}

// ---------------- fused prep: cast x/qkv_w/proj_w -> bf16, RoPE table ----------------
// One dispatch replaces 3 cast launches + rope launch. (R3 note: total-duration
// noise is +-15-20us run-to-run; fusion kept because it is strictly fewer
// launches, but no measured credit claimed.)
__global__ __launch_bounds__(256) void prep_kernel(
    const float* __restrict__ x, const float* __restrict__ qkv_w,
    const float* __restrict__ proj_w, __hip_bfloat16* __restrict__ xb,
    __hip_bfloat16* __restrict__ w1b, __hip_bfloat16* __restrict__ w2b,
    float* __restrict__ cosT, float* __restrict__ sinT) {
  const int N1 = 25088 * 768 / 4;          // 4,816,896
  const int N2 = 2304 * 768 / 4;           // 442,368
  const int N3 = 768 * 768 / 4;            // 147,456
  int i = blockIdx.x * 256 + threadIdx.x;
  const float* src;
  __hip_bfloat16* dst;
  int idx;
  if (i < N1) {
    src = x; dst = xb; idx = i;
  } else if (i < N1 + N2) {
    src = qkv_w; dst = w1b; idx = i - N1;
  } else if (i < N1 + N2 + N3) {
    src = proj_w; dst = w2b; idx = i - N1 - N2;
  } else {
    int r = i - (N1 + N2 + N3);
    if (r < 196 * 64) {
      int t = r >> 6, d = r & 63;
      int c = d & 31;                       // emb = concat([e,e]) over 32
      float pos = (c < 16) ? (float)(t / 14) : (float)(t % 14);  // h then w
      int j = c & 15;                       // freq index
      float invf = expf(-(float)j * 0.5756462732485114f);  // 10000^(-j/16)
      float ang = pos * invf;
      cosT[r] = cosf(ang);
      sinT[r] = sinf(ang);
    }
    return;
  }
  float4 v = reinterpret_cast<const float4*>(src)[idx];
  ushort4 o;
  o.x = __builtin_bit_cast(unsigned short, __float2bfloat16(v.x));
  o.y = __builtin_bit_cast(unsigned short, __float2bfloat16(v.y));
  o.z = __builtin_bit_cast(unsigned short, __float2bfloat16(v.z));
  o.w = __builtin_bit_cast(unsigned short, __float2bfloat16(v.w));
  reinterpret_cast<ushort4*>(dst)[idx] = o;
}

// ---------------- QKV GEMM: [25088x768] x [2304x768]^T + bias, fused RoPE,
//                  scatter to q/k/v [128][12][196][64] bf16 ----------------
// BK=64: 12 K-iters. LDS 32 KB. XOR chunk-swizzle on global source.
// R1 post-mortem: 256^2 8-phase port regressed (K=768 = 12 K-tiles, grid 882 =
// 3.44 ragged rounds at 1 block/CU -> no steady state). This m97-structure at
// 2.25 blocks/CU TLP is the measured local optimum (~118 us, 33% MfmaUtil).
__global__ __launch_bounds__(256) void gemm_qkv_kernel(
    const __hip_bfloat16* __restrict__ A, const __hip_bfloat16* __restrict__ W,
    const float* __restrict__ bias, const float* __restrict__ cosT,
    const float* __restrict__ sinT, __hip_bfloat16* __restrict__ qb,
    __hip_bfloat16* __restrict__ kb, __hip_bfloat16* __restrict__ vb) {
  __shared__ __align__(16) __hip_bfloat16 As[128 * 64];
  __shared__ __align__(16) __hip_bfloat16 Bs[128 * 64];
  const int tid = threadIdx.x;
  const int id = blockIdx.x;
  const int sup = id / 72, rem = id % 72;   // supertile = 4 bm x 18 bn
  const int bm = sup * 4 + rem / 18;
  const int bn = rem % 18;
  const int lane = tid & 63, wv = tid >> 6;
  const int wm = wv >> 1, wn = wv & 1;
  const int quad = lane >> 4, ln = lane & 15;

  const int r0 = tid >> 3;
  const int csw = ((tid & 7) ^ (r0 & 7)) * 8;
  const __hip_bfloat16* Ag = A + ((long)(bm * 128 + r0) * 768 + csw);
  const __hip_bfloat16* Wg = W + ((long)(bn * 128 + r0) * 768 + csw);
  __hip_bfloat16* As0 = As + tid * 8;
  __hip_bfloat16* Bs0 = Bs + tid * 8;

  const int c0 = (quad ^ (ln & 7)) * 8;
  const int c1 = c0 ^ 32;

  f32x4 acc[4][4];
#pragma unroll
  for (int i = 0; i < 4; i++)
#pragma unroll
    for (int j = 0; j < 4; j++) acc[i][j] = (f32x4){0.f, 0.f, 0.f, 0.f};

  for (int k0 = 0; k0 < 768; k0 += 64) {
    GLD16(Ag + k0,            As0);
    GLD16(Ag + 32 * 768 + k0, As0 + 2048);
    GLD16(Ag + 64 * 768 + k0, As0 + 4096);
    GLD16(Ag + 96 * 768 + k0, As0 + 6144);
    GLD16(Wg + k0,            Bs0);
    GLD16(Wg + 32 * 768 + k0, Bs0 + 2048);
    GLD16(Wg + 64 * 768 + k0, Bs0 + 4096);
    GLD16(Wg + 96 * 768 + k0, Bs0 + 6144);
    __syncthreads();
#pragma unroll
    for (int kk = 0; kk < 2; kk++) {
      const int cc = kk ? c1 : c0;
      short8 af[4], bf[4];
#pragma unroll
      for (int i = 0; i < 4; i++)
        af[i] = *(const short8*)(As + (wm * 64 + i * 16 + ln) * 64 + cc);
#pragma unroll
      for (int j = 0; j < 4; j++)
        bf[j] = *(const short8*)(Bs + (wn * 64 + j * 16 + ln) * 64 + cc);
#pragma unroll
      for (int i = 0; i < 4; i++)
#pragma unroll
        for (int j = 0; j < 4; j++) acc[i][j] = mfma_bf16(af[i], bf[j], acc[i][j]);
    }
    __syncthreads();
  }

  const int ncolbase = bn * 128 + wn * 64;  // multiple of 64
  const int s = ncolbase / 768;             // 0=q 1=k 2=v (wave-uniform)
  const int hh = (ncolbase % 768) >> 6;     // head (wave-uniform)
  __hip_bfloat16* outb = (s == 0) ? qb : ((s == 1) ? kb : vb);
  float bi[4];
#pragma unroll
  for (int j = 0; j < 4; j++) bi[j] = bias[ncolbase + j * 16 + ln];
  const bool dorope = (s < 2);

#pragma unroll
  for (int i = 0; i < 4; i++) {
#pragma unroll
    for (int r = 0; r < 4; r++) {
      int m = bm * 128 + wm * 64 + i * 16 + quad * 4 + r;  // row (C layout: quad*4+reg)
      int b = m / 196, t = m - b * 196;
      float v0 = acc[i][0][r] + bi[0];
      float v1 = acc[i][1][r] + bi[1];
      float v2 = acc[i][2][r] + bi[2];
      float v3 = acc[i][3][r] + bi[3];
      if (dorope) {
        const float* ct = cosT + t * 64 + ln;
        const float* st = sinT + t * 64 + ln;
        float c0f = ct[0], c1f = ct[16], c2f = ct[32], c3f = ct[48];
        float s0 = st[0], s1 = st[16], s2 = st[32], s3 = st[48];
        float w0 = v0 * c0f - v2 * s0;   // d<32: rh = -x[d+32]
        float w1 = v1 * c1f - v3 * s1;
        float w2 = v2 * c2f + v0 * s2;   // d>=32: rh = +x[d-32]
        float w3 = v3 * c3f + v1 * s3;
        v0 = w0; v1 = w1; v2 = w2; v3 = w3;
      }
      __hip_bfloat16* op = outb + ((long)(b * 12 + hh) * 196 + t) * 64 + ln;
      op[0]  = __float2bfloat16(v0);
      op[16] = __float2bfloat16(v1);
      op[32] = __float2bfloat16(v2);
      op[48] = __float2bfloat16(v3);
    }
  }
}

// ---------------- attention: one block per (b,h), 4 waves ----------------
// R3 REWRITE (occupancy): old version used a full per-wave 16x224 P tile
// (Ps 29.7 KB) -> LDS 59.4 KB -> 2 blocks/CU -> 2 waves/SIMD, latency-bound.
// PV only ever consumes P in 32-key chunks (one b128 per kt), so exp+store+PV
// are now fused per 32-key group through a tiny per-wave [16][40] chunk buffer
// (stride 40 elems: keeps all b128 reads 16B-aligned; bank-uniform 8/bank =
// structural floor). sm reduction is linear -> moved after PV. LDS 34.8 KB ->
// 4 blocks/CU (16 waves/CU, 2x latency hiding). No inter-wave sync needed:
// chunk buffer is per-wave, LDS ops in-order within a wave.
// V-stage rotation (derived): unrotated, the 8 scatter stores/thread put all
// 8 c-chunks on one 4-bank set (928 words == 0 mod 32) -> ~8-way write
// conflict; u=(uu+cq)&7 spreads them over 8 distinct bank clusters.
__global__ __launch_bounds__(256, 4) void attn_kernel(
    const __hip_bfloat16* __restrict__ qb, const __hip_bfloat16* __restrict__ kb,
    const __hip_bfloat16* __restrict__ vb, __hip_bfloat16* __restrict__ att) {
  __shared__ __align__(16) __hip_bfloat16 Vt[64 * 232];    // V^T [d][key], keys padded to 224
  __shared__ __align__(16) __hip_bfloat16 Ps[4][16 * 40];  // per-wave 32-key P chunk
  const int bh = blockIdx.x;
  const int b = bh / 12, h = bh - b * 12;
  const int tid = threadIdx.x;
  const int lane = tid & 63, wv = tid >> 6;
  const int quad = lane >> 4, ln = lane & 15;
  const __hip_bfloat16* qg = qb + (long)bh * (196 * 64);
  const __hip_bfloat16* kg = kb + (long)bh * (196 * 64);
  const __hip_bfloat16* vg = vb + (long)bh * (196 * 64);

  // stage V transposed (zero-pad keys 196..223), rotated scatter
  for (int ch = tid; ch < 224 * 8; ch += 256) {
    int row = ch >> 3, cq = ch & 7, c = cq * 8;
    unsigned short vals[8] = {0, 0, 0, 0, 0, 0, 0, 0};
    if (row < 196) *(uint4*)vals = *(const uint4*)(vg + row * 64 + c);
#pragma unroll
    for (int uu = 0; uu < 8; uu++) {
      int u = (uu + cq) & 7;   // de-alias banks across the 8 c-chunks
      ((unsigned short*)Vt)[(c + u) * 232 + row] = vals[u];
    }
  }
  __syncthreads();

  __hip_bfloat16* Pw = &Ps[wv][0];

  for (int qt = wv; qt < 13; qt += 4) {
    int tok = qt * 16 + ln;
    if (tok > 195) tok = 195;              // clamped rows masked at store
    short8 aq0 = *(const short8*)(qg + tok * 64 + quad * 8);
    short8 aq1 = *(const short8*)(qg + tok * 64 + 32 + quad * 8);

    f32x4 sacc[13];
#pragma unroll
    for (int ct = 0; ct < 13; ct++) {
      int krow = ct * 16 + ln;
      if (krow > 195) krow = 195;          // garbage cols zeroed below
      const __hip_bfloat16* kp = kg + krow * 64 + quad * 8;
      short8 b0 = *(const short8*)kp;
      short8 b1 = *(const short8*)(kp + 32);
      f32x4 cacc = (f32x4){0.f, 0.f, 0.f, 0.f};
      cacc = mfma_bf16(aq0, b0, cacc);
      cacc = mfma_bf16(aq1, b1, cacc);
      sacc[ct] = cacc;
    }

    // fused no-max softmax + PV, 32 keys per group through the chunk buffer.
    // p = exp(s/8) (|logit| <~ 7, fp32-safe); normalization after PV (linear).
    float sm[4] = {0.f, 0.f, 0.f, 0.f};
    f32x4 o[4];
#pragma unroll
    for (int j = 0; j < 4; j++) o[j] = (f32x4){0.f, 0.f, 0.f, 0.f};

#pragma unroll
    for (int g = 0; g < 6; g++) {          // keys 0..191: all valid
#pragma unroll
      for (int h2 = 0; h2 < 2; h2++) {
        int ct = 2 * g + h2;
#pragma unroll
        for (int r = 0; r < 4; r++) {
          float p = __expf(sacc[ct][r] * 0.125f);
          sm[r] += p;
          Pw[(quad * 4 + r) * 40 + h2 * 16 + ln] = __float2bfloat16(p);
        }
      }
      asm volatile("" ::: "memory");       // order P stores vs b128 reload
      short8 pa = *(const short8*)(Pw + ln * 40 + quad * 8);
#pragma unroll
      for (int j = 0; j < 4; j++) {
        short8 bv = *(const short8*)(Vt + (j * 16 + ln) * 232 + g * 32 + quad * 8);
        o[j] = mfma_bf16(pa, bv, o[j]);
      }
      asm volatile("" ::: "memory");
    }
    {                                      // group 6: keys 192..207 (ct=12), 208..223 zero
#pragma unroll
      for (int r = 0; r < 4; r++) {
        float p = (ln < 4) ? __expf(sacc[12][r] * 0.125f) : 0.f;  // 192+ln < 196
        sm[r] += p;
        Pw[(quad * 4 + r) * 40 + ln] = __float2bfloat16(p);
        Pw[(quad * 4 + r) * 40 + 16 + ln] = __float2bfloat16(0.f);
      }
      asm volatile("" ::: "memory");
      short8 pa = *(const short8*)(Pw + ln * 40 + quad * 8);
#pragma unroll
      for (int j = 0; j < 4; j++) {
        short8 bv = *(const short8*)(Vt + (j * 16 + ln) * 232 + 192 + quad * 8);
        o[j] = mfma_bf16(pa, bv, o[j]);
      }
      asm volatile("" ::: "memory");
    }

#pragma unroll
    for (int mk = 1; mk < 16; mk <<= 1) {
#pragma unroll
      for (int r = 0; r < 4; r++) sm[r] += __shfl_xor(sm[r], mk, 64);
    }

    float rl[4];
#pragma unroll
    for (int r = 0; r < 4; r++) rl[r] = 1.0f / sm[r];
    int trow = qt * 16 + quad * 4;
#pragma unroll
    for (int r = 0; r < 4; r++) {
      int t = trow + r;
      if (t < 196) {
        __hip_bfloat16* op = att + (long)(b * 196 + t) * 768 + h * 64 + ln;
#pragma unroll
        for (int j = 0; j < 4; j++) op[j * 16] = __float2bfloat16(o[j][r] * rl[r]);
      }
    }
  }
}

// ---------------- proj GEMM: [25088x768] x [768x768]^T + bias -> fp32 out ----------------
// BK=64 + XOR chunk-swizzle (see gemm_qkv).
__global__ __launch_bounds__(256) void gemm_proj_kernel(
    const __hip_bfloat16* __restrict__ A, const __hip_bfloat16* __restrict__ W,
    const float* __restrict__ bias, float* __restrict__ out) {
  __shared__ __align__(16) __hip_bfloat16 As[128 * 64];
  __shared__ __align__(16) __hip_bfloat16 Bs[128 * 64];
  const int tid = threadIdx.x;
  const int id = blockIdx.x;
  const int sup = id / 24, rem = id % 24;   // supertile = 4 bm x 6 bn
  const int bm = sup * 4 + rem / 6;
  const int bn = rem % 6;
  const int lane = tid & 63, wv = tid >> 6;
  const int wm = wv >> 1, wn = wv & 1;
  const int quad = lane >> 4, ln = lane & 15;

  const int r0 = tid >> 3;
  const int csw = ((tid & 7) ^ (r0 & 7)) * 8;
  const __hip_bfloat16* Ag = A + ((long)(bm * 128 + r0) * 768 + csw);
  const __hip_bfloat16* Wg = W + ((long)(bn * 128 + r0) * 768 + csw);
  __hip_bfloat16* As0 = As + tid * 8;
  __hip_bfloat16* Bs0 = Bs + tid * 8;

  const int c0 = (quad ^ (ln & 7)) * 8;
  const int c1 = c0 ^ 32;

  f32x4 acc[4][4];
#pragma unroll
  for (int i = 0; i < 4; i++)
#pragma unroll
    for (int j = 0; j < 4; j++) acc[i][j] = (f32x4){0.f, 0.f, 0.f, 0.f};

  for (int k0 = 0; k0 < 768; k0 += 64) {
    GLD16(Ag + k0,            As0);
    GLD16(Ag + 32 * 768 + k0, As0 + 2048);
    GLD16(Ag + 64 * 768 + k0, As0 + 4096);
    GLD16(Ag + 96 * 768 + k0, As0 + 6144);
    GLD16(Wg + k0,            Bs0);
    GLD16(Wg + 32 * 768 + k0, Bs0 + 2048);
    GLD16(Wg + 64 * 768 + k0, Bs0 + 4096);
    GLD16(Wg + 96 * 768 + k0, Bs0 + 6144);
    __syncthreads();
#pragma unroll
    for (int kk = 0; kk < 2; kk++) {
      const int cc = kk ? c1 : c0;
      short8 af[4], bf[4];
#pragma unroll
      for (int i = 0; i < 4; i++)
        af[i] = *(const short8*)(As + (wm * 64 + i * 16 + ln) * 64 + cc);
#pragma unroll
      for (int j = 0; j < 4; j++)
        bf[j] = *(const short8*)(Bs + (wn * 64 + j * 16 + ln) * 64 + cc);
#pragma unroll
      for (int i = 0; i < 4; i++)
#pragma unroll
        for (int j = 0; j < 4; j++) acc[i][j] = mfma_bf16(af[i], bf[j], acc[i][j]);
    }
    __syncthreads();
  }

  const int ncolbase = bn * 128 + wn * 64;
  float bi[4];
#pragma unroll
  for (int j = 0; j < 4; j++) bi[j] = bias[ncolbase + j * 16 + ln];
#pragma unroll
  for (int i = 0; i < 4; i++) {
#pragma unroll
    for (int r = 0; r < 4; r++) {
      int m = bm * 128 + wm * 64 + i * 16 + quad * 4 + r;
      float* op = out + (long)m * 768 + ncolbase + ln;
      op[0]  = acc[i][0][r] + bi[0];
      op[16] = acc[i][1][r] + bi[1];
      op[32] = acc[i][2][r] + bi[2];
      op[48] = acc[i][3][r] + bi[3];
    }
  }
}

extern "C" void kernel_launch(void* const* d_in, const int* in_sizes, int n_in,
                              void* d_out, int out_size, void* d_ws, size_t ws_size,
                              hipStream_t stream) {
  const float* x      = (const float*)d_in[0];
  const float* qkv_w  = (const float*)d_in[1];
  const float* qkv_b  = (const float*)d_in[2];
  const float* proj_w = (const float*)d_in[3];
  const float* proj_b = (const float*)d_in[4];
  float* out = (float*)d_out;
  (void)in_sizes; (void)n_in; (void)out_size; (void)ws_size;

  // workspace layout (~159 MB; attb aliases xb which is dead after QKV GEMM)
  char* ws = (char*)d_ws;
  size_t off = 0;
  auto alloc = [&](size_t bytes) -> void* {
    void* p = (void*)(ws + off);
    off += (bytes + 255) & ~(size_t)255;
    return p;
  };
  const size_t MB0 = (size_t)25088 * 768 * 2;  // 38,535,168 B
  __hip_bfloat16* xb   = (__hip_bfloat16*)alloc(MB0);
  __hip_bfloat16* w1b  = (__hip_bfloat16*)alloc((size_t)2304 * 768 * 2);
  __hip_bfloat16* w2b  = (__hip_bfloat16*)alloc((size_t)768 * 768 * 2);
  float* cosT          = (float*)alloc(196 * 64 * 4);
  float* sinT          = (float*)alloc(196 * 64 * 4);
  __hip_bfloat16* qbuf = (__hip_bfloat16*)alloc(MB0);
  __hip_bfloat16* kbuf = (__hip_bfloat16*)alloc(MB0);
  __hip_bfloat16* vbuf = (__hip_bfloat16*)alloc(MB0);
  __hip_bfloat16* attb = xb;  // alias: xb dead after gemm_qkv

  // prep index space: 4,816,896 + 442,368 + 147,456 float4-casts + 12,544 rope
  // = 5,419,264 threads = 21,169 blocks x 256 (exact).
  prep_kernel<<<21169, 256, 0, stream>>>(x, qkv_w, proj_w, xb, w1b, w2b, cosT, sinT);
  gemm_qkv_kernel<<<3528, 256, 0, stream>>>(xb, w1b, qkv_b, cosT, sinT,
                                            qbuf, kbuf, vbuf);
  attn_kernel<<<1536, 256, 0, stream>>>(qbuf, kbuf, vbuf, attb);
  gemm_proj_kernel<<<1176, 256, 0, stream>>>(attb, w2b, proj_b, out);
}

// Round 5
// 397.226 us; speedup vs baseline: 1.1440x; 1.1440x over previous
//
#include <hip/hip_runtime.h>
#include <hip/hip_bf16.h>

typedef __attribute__((ext_vector_type(8))) short short8;
typedef __attribute__((ext_vector_type(4))) float f32x4;

#define GLD16(gp, lp) \
  __builtin_amdgcn_global_load_lds((const __attribute__((address_space(1))) void*)(gp), \
                                   (__attribute__((address_space(3))) void*)(lp), 16, 0, 0)

__device__ __forceinline__ f32x4 mfma_bf16(short8 a, short8 b, f32x4 c) {
  return __builtin_amdgcn_mfma_f32_16x16x32_bf16(a, b, c, 0, 0, 0);
}

// ---------------- fused prep: cast x/qkv_w/proj_w -> bf16, RoPE table ----------------
__global__ __launch_bounds__(256) void prep_kernel(
    const float* __restrict__ x, const float* __restrict__ qkv_w,
    const float* __restrict__ proj_w, __hip_bfloat16* __restrict__ xb,
    __hip_bfloat16* __restrict__ w1b, __hip_bfloat16* __restrict__ w2b,
    float* __restrict__ cosT, float* __restrict__ sinT) {
  const int N1 = 25088 * 768 / 4;          // 4,816,896
  const int N2 = 2304 * 768 / 4;           // 442,368
  const int N3 = 768 * 768 / 4;            // 147,456
  int i = blockIdx.x * 256 + threadIdx.x;
  const float* src;
  __hip_bfloat16* dst;
  int idx;
  if (i < N1) {
    src = x; dst = xb; idx = i;
  } else if (i < N1 + N2) {
    src = qkv_w; dst = w1b; idx = i - N1;
  } else if (i < N1 + N2 + N3) {
    src = proj_w; dst = w2b; idx = i - N1 - N2;
  } else {
    int r = i - (N1 + N2 + N3);
    if (r < 196 * 64) {
      int t = r >> 6, d = r & 63;
      int c = d & 31;                       // emb = concat([e,e]) over 32
      float pos = (c < 16) ? (float)(t / 14) : (float)(t % 14);  // h then w
      int j = c & 15;                       // freq index
      float invf = expf(-(float)j * 0.5756462732485114f);  // 10000^(-j/16)
      float ang = pos * invf;
      cosT[r] = cosf(ang);
      sinT[r] = sinf(ang);
    }
    return;
  }
  float4 v = reinterpret_cast<const float4*>(src)[idx];
  ushort4 o;
  o.x = __builtin_bit_cast(unsigned short, __float2bfloat16(v.x));
  o.y = __builtin_bit_cast(unsigned short, __float2bfloat16(v.y));
  o.z = __builtin_bit_cast(unsigned short, __float2bfloat16(v.z));
  o.w = __builtin_bit_cast(unsigned short, __float2bfloat16(v.w));
  reinterpret_cast<ushort4*>(dst)[idx] = o;
}

// ---------------- QKV GEMM: [25088x768] x [2304x768]^T + bias, fused RoPE,
//                  scatter to q/k/v [128][12][196][64] bf16 ----------------
// m97-structure, BK=64, XOR chunk-swizzle. Measured local optimum (~118 us,
// 33% MfmaUtil); R1's 256^2 8-phase port regressed (K too short, grid ragged).
__global__ __launch_bounds__(256) void gemm_qkv_kernel(
    const __hip_bfloat16* __restrict__ A, const __hip_bfloat16* __restrict__ W,
    const float* __restrict__ bias, const float* __restrict__ cosT,
    const float* __restrict__ sinT, __hip_bfloat16* __restrict__ qb,
    __hip_bfloat16* __restrict__ kb, __hip_bfloat16* __restrict__ vb) {
  __shared__ __align__(16) __hip_bfloat16 As[128 * 64];
  __shared__ __align__(16) __hip_bfloat16 Bs[128 * 64];
  const int tid = threadIdx.x;
  const int id = blockIdx.x;
  const int sup = id / 72, rem = id % 72;   // supertile = 4 bm x 18 bn
  const int bm = sup * 4 + rem / 18;
  const int bn = rem % 18;
  const int lane = tid & 63, wv = tid >> 6;
  const int wm = wv >> 1, wn = wv & 1;
  const int quad = lane >> 4, ln = lane & 15;

  const int r0 = tid >> 3;
  const int csw = ((tid & 7) ^ (r0 & 7)) * 8;
  const __hip_bfloat16* Ag = A + ((long)(bm * 128 + r0) * 768 + csw);
  const __hip_bfloat16* Wg = W + ((long)(bn * 128 + r0) * 768 + csw);
  __hip_bfloat16* As0 = As + tid * 8;
  __hip_bfloat16* Bs0 = Bs + tid * 8;

  const int c0 = (quad ^ (ln & 7)) * 8;
  const int c1 = c0 ^ 32;

  f32x4 acc[4][4];
#pragma unroll
  for (int i = 0; i < 4; i++)
#pragma unroll
    for (int j = 0; j < 4; j++) acc[i][j] = (f32x4){0.f, 0.f, 0.f, 0.f};

  for (int k0 = 0; k0 < 768; k0 += 64) {
    GLD16(Ag + k0,            As0);
    GLD16(Ag + 32 * 768 + k0, As0 + 2048);
    GLD16(Ag + 64 * 768 + k0, As0 + 4096);
    GLD16(Ag + 96 * 768 + k0, As0 + 6144);
    GLD16(Wg + k0,            Bs0);
    GLD16(Wg + 32 * 768 + k0, Bs0 + 2048);
    GLD16(Wg + 64 * 768 + k0, Bs0 + 4096);
    GLD16(Wg + 96 * 768 + k0, Bs0 + 6144);
    __syncthreads();
#pragma unroll
    for (int kk = 0; kk < 2; kk++) {
      const int cc = kk ? c1 : c0;
      short8 af[4], bf[4];
#pragma unroll
      for (int i = 0; i < 4; i++)
        af[i] = *(const short8*)(As + (wm * 64 + i * 16 + ln) * 64 + cc);
#pragma unroll
      for (int j = 0; j < 4; j++)
        bf[j] = *(const short8*)(Bs + (wn * 64 + j * 16 + ln) * 64 + cc);
#pragma unroll
      for (int i = 0; i < 4; i++)
#pragma unroll
        for (int j = 0; j < 4; j++) acc[i][j] = mfma_bf16(af[i], bf[j], acc[i][j]);
    }
    __syncthreads();
  }

  const int ncolbase = bn * 128 + wn * 64;  // multiple of 64
  const int s = ncolbase / 768;             // 0=q 1=k 2=v (wave-uniform)
  const int hh = (ncolbase % 768) >> 6;     // head (wave-uniform)
  __hip_bfloat16* outb = (s == 0) ? qb : ((s == 1) ? kb : vb);
  float bi[4];
#pragma unroll
  for (int j = 0; j < 4; j++) bi[j] = bias[ncolbase + j * 16 + ln];
  const bool dorope = (s < 2);

#pragma unroll
  for (int i = 0; i < 4; i++) {
#pragma unroll
    for (int r = 0; r < 4; r++) {
      int m = bm * 128 + wm * 64 + i * 16 + quad * 4 + r;  // row (C layout: quad*4+reg)
      int b = m / 196, t = m - b * 196;
      float v0 = acc[i][0][r] + bi[0];
      float v1 = acc[i][1][r] + bi[1];
      float v2 = acc[i][2][r] + bi[2];
      float v3 = acc[i][3][r] + bi[3];
      if (dorope) {
        const float* ct = cosT + t * 64 + ln;
        const float* st = sinT + t * 64 + ln;
        float c0f = ct[0], c1f = ct[16], c2f = ct[32], c3f = ct[48];
        float s0 = st[0], s1 = st[16], s2 = st[32], s3 = st[48];
        float w0 = v0 * c0f - v2 * s0;   // d<32: rh = -x[d+32]
        float w1 = v1 * c1f - v3 * s1;
        float w2 = v2 * c2f + v0 * s2;   // d>=32: rh = +x[d-32]
        float w3 = v3 * c3f + v1 * s3;
        v0 = w0; v1 = w1; v2 = w2; v3 = w3;
      }
      __hip_bfloat16* op = outb + ((long)(b * 12 + hh) * 196 + t) * 64 + ln;
      op[0]  = __float2bfloat16(v0);
      op[16] = __float2bfloat16(v1);
      op[32] = __float2bfloat16(v2);
      op[48] = __float2bfloat16(v3);
    }
  }
}

// ---------------- attention: one block per (b,h), 4 waves ----------------
// R4 POST-MORTEM: __launch_bounds__(256,4) strangled the allocator to 64 VGPRs
// (live state ~110: sacc 52 + o 16 + aq 8 + addr) -> sacc spilled to scratch.
// Counter proof: FETCH 218.6 = 115.5 ideal + ~104 spill-reload; WRITE 143.6 =
// 38.5 ideal + ~104 spill-store (both match within 1 MB). No store
// amplification, no L2 thrash -- the ONLY defect was the spill.
// R5: drop the min-waves clamp. LDS 38.9 KB still allows 4 blocks/CU; at
// ~100-128 VGPR (no spill) that occupancy is now real.
__global__ __launch_bounds__(256) void attn_kernel(
    const __hip_bfloat16* __restrict__ qb, const __hip_bfloat16* __restrict__ kb,
    const __hip_bfloat16* __restrict__ vb, __hip_bfloat16* __restrict__ att) {
  __shared__ __align__(16) __hip_bfloat16 Vt[64 * 232];    // V^T [d][key], keys padded to 224
  __shared__ __align__(16) __hip_bfloat16 Ps[4][16 * 40];  // per-wave 32-key P chunk
  const int bh = blockIdx.x;
  const int b = bh / 12, h = bh - b * 12;
  const int tid = threadIdx.x;
  const int lane = tid & 63, wv = tid >> 6;
  const int quad = lane >> 4, ln = lane & 15;
  const __hip_bfloat16* qg = qb + (long)bh * (196 * 64);
  const __hip_bfloat16* kg = kb + (long)bh * (196 * 64);
  const __hip_bfloat16* vg = vb + (long)bh * (196 * 64);

  // stage V transposed (zero-pad keys 196..223), rotated scatter
  for (int ch = tid; ch < 224 * 8; ch += 256) {
    int row = ch >> 3, cq = ch & 7, c = cq * 8;
    unsigned short vals[8] = {0, 0, 0, 0, 0, 0, 0, 0};
    if (row < 196) *(uint4*)vals = *(const uint4*)(vg + row * 64 + c);
#pragma unroll
    for (int uu = 0; uu < 8; uu++) {
      int u = (uu + cq) & 7;   // de-alias banks across the 8 c-chunks
      ((unsigned short*)Vt)[(c + u) * 232 + row] = vals[u];
    }
  }
  __syncthreads();

  __hip_bfloat16* Pw = &Ps[wv][0];

  for (int qt = wv; qt < 13; qt += 4) {
    int tok = qt * 16 + ln;
    if (tok > 195) tok = 195;              // clamped rows masked at store
    short8 aq0 = *(const short8*)(qg + tok * 64 + quad * 8);
    short8 aq1 = *(const short8*)(qg + tok * 64 + 32 + quad * 8);

    f32x4 sacc[13];
#pragma unroll
    for (int ct = 0; ct < 13; ct++) {
      int krow = ct * 16 + ln;
      if (krow > 195) krow = 195;          // garbage cols zeroed below
      const __hip_bfloat16* kp = kg + krow * 64 + quad * 8;
      short8 b0 = *(const short8*)kp;
      short8 b1 = *(const short8*)(kp + 32);
      f32x4 cacc = (f32x4){0.f, 0.f, 0.f, 0.f};
      cacc = mfma_bf16(aq0, b0, cacc);
      cacc = mfma_bf16(aq1, b1, cacc);
      sacc[ct] = cacc;
    }

    // fused no-max softmax + PV, 32 keys per group through the chunk buffer.
    // p = exp(s/8) (|logit| <~ 7, fp32-safe); normalization after PV (linear).
    float sm[4] = {0.f, 0.f, 0.f, 0.f};
    f32x4 o[4];
#pragma unroll
    for (int j = 0; j < 4; j++) o[j] = (f32x4){0.f, 0.f, 0.f, 0.f};

#pragma unroll
    for (int g = 0; g < 6; g++) {          // keys 0..191: all valid
#pragma unroll
      for (int h2 = 0; h2 < 2; h2++) {
        int ct = 2 * g + h2;
#pragma unroll
        for (int r = 0; r < 4; r++) {
          float p = __expf(sacc[ct][r] * 0.125f);
          sm[r] += p;
          Pw[(quad * 4 + r) * 40 + h2 * 16 + ln] = __float2bfloat16(p);
        }
      }
      asm volatile("" ::: "memory");       // order P stores vs b128 reload
      short8 pa = *(const short8*)(Pw + ln * 40 + quad * 8);
#pragma unroll
      for (int j = 0; j < 4; j++) {
        short8 bv = *(const short8*)(Vt + (j * 16 + ln) * 232 + g * 32 + quad * 8);
        o[j] = mfma_bf16(pa, bv, o[j]);
      }
      asm volatile("" ::: "memory");
    }
    {                                      // group 6: keys 192..207 (ct=12), 208..223 zero
#pragma unroll
      for (int r = 0; r < 4; r++) {
        float p = (ln < 4) ? __expf(sacc[12][r] * 0.125f) : 0.f;  // 192+ln < 196
        sm[r] += p;
        Pw[(quad * 4 + r) * 40 + ln] = __float2bfloat16(p);
        Pw[(quad * 4 + r) * 40 + 16 + ln] = __float2bfloat16(0.f);
      }
      asm volatile("" ::: "memory");
      short8 pa = *(const short8*)(Pw + ln * 40 + quad * 8);
#pragma unroll
      for (int j = 0; j < 4; j++) {
        short8 bv = *(const short8*)(Vt + (j * 16 + ln) * 232 + 192 + quad * 8);
        o[j] = mfma_bf16(pa, bv, o[j]);
      }
      asm volatile("" ::: "memory");
    }

#pragma unroll
    for (int mk = 1; mk < 16; mk <<= 1) {
#pragma unroll
      for (int r = 0; r < 4; r++) sm[r] += __shfl_xor(sm[r], mk, 64);
    }

    float rl[4];
#pragma unroll
    for (int r = 0; r < 4; r++) rl[r] = 1.0f / sm[r];
    int trow = qt * 16 + quad * 4;
#pragma unroll
    for (int r = 0; r < 4; r++) {
      int t = trow + r;
      if (t < 196) {
        __hip_bfloat16* op = att + (long)(b * 196 + t) * 768 + h * 64 + ln;
#pragma unroll
        for (int j = 0; j < 4; j++) op[j * 16] = __float2bfloat16(o[j][r] * rl[r]);
      }
    }
  }
}

// ---------------- proj GEMM: [25088x768] x [768x768]^T + bias -> fp32 out ----------------
// BK=64 + XOR chunk-swizzle (see gemm_qkv).
__global__ __launch_bounds__(256) void gemm_proj_kernel(
    const __hip_bfloat16* __restrict__ A, const __hip_bfloat16* __restrict__ W,
    const float* __restrict__ bias, float* __restrict__ out) {
  __shared__ __align__(16) __hip_bfloat16 As[128 * 64];
  __shared__ __align__(16) __hip_bfloat16 Bs[128 * 64];
  const int tid = threadIdx.x;
  const int id = blockIdx.x;
  const int sup = id / 24, rem = id % 24;   // supertile = 4 bm x 6 bn
  const int bm = sup * 4 + rem / 6;
  const int bn = rem % 6;
  const int lane = tid & 63, wv = tid >> 6;
  const int wm = wv >> 1, wn = wv & 1;
  const int quad = lane >> 4, ln = lane & 15;

  const int r0 = tid >> 3;
  const int csw = ((tid & 7) ^ (r0 & 7)) * 8;
  const __hip_bfloat16* Ag = A + ((long)(bm * 128 + r0) * 768 + csw);
  const __hip_bfloat16* Wg = W + ((long)(bn * 128 + r0) * 768 + csw);
  __hip_bfloat16* As0 = As + tid * 8;
  __hip_bfloat16* Bs0 = Bs + tid * 8;

  const int c0 = (quad ^ (ln & 7)) * 8;
  const int c1 = c0 ^ 32;

  f32x4 acc[4][4];
#pragma unroll
  for (int i = 0; i < 4; i++)
#pragma unroll
    for (int j = 0; j < 4; j++) acc[i][j] = (f32x4){0.f, 0.f, 0.f, 0.f};

  for (int k0 = 0; k0 < 768; k0 += 64) {
    GLD16(Ag + k0,            As0);
    GLD16(Ag + 32 * 768 + k0, As0 + 2048);
    GLD16(Ag + 64 * 768 + k0, As0 + 4096);
    GLD16(Ag + 96 * 768 + k0, As0 + 6144);
    GLD16(Wg + k0,            Bs0);
    GLD16(Wg + 32 * 768 + k0, Bs0 + 2048);
    GLD16(Wg + 64 * 768 + k0, Bs0 + 4096);
    GLD16(Wg + 96 * 768 + k0, Bs0 + 6144);
    __syncthreads();
#pragma unroll
    for (int kk = 0; kk < 2; kk++) {
      const int cc = kk ? c1 : c0;
      short8 af[4], bf[4];
#pragma unroll
      for (int i = 0; i < 4; i++)
        af[i] = *(const short8*)(As + (wm * 64 + i * 16 + ln) * 64 + cc);
#pragma unroll
      for (int j = 0; j < 4; j++)
        bf[j] = *(const short8*)(Bs + (wn * 64 + j * 16 + ln) * 64 + cc);
#pragma unroll
      for (int i = 0; i < 4; i++)
#pragma unroll
        for (int j = 0; j < 4; j++) acc[i][j] = mfma_bf16(af[i], bf[j], acc[i][j]);
    }
    __syncthreads();
  }

  const int ncolbase = bn * 128 + wn * 64;
  float bi[4];
#pragma unroll
  for (int j = 0; j < 4; j++) bi[j] = bias[ncolbase + j * 16 + ln];
#pragma unroll
  for (int i = 0; i < 4; i++) {
#pragma unroll
    for (int r = 0; r < 4; r++) {
      int m = bm * 128 + wm * 64 + i * 16 + quad * 4 + r;
      float* op = out + (long)m * 768 + ncolbase + ln;
      op[0]  = acc[i][0][r] + bi[0];
      op[16] = acc[i][1][r] + bi[1];
      op[32] = acc[i][2][r] + bi[2];
      op[48] = acc[i][3][r] + bi[3];
    }
  }
}

extern "C" void kernel_launch(void* const* d_in, const int* in_sizes, int n_in,
                              void* d_out, int out_size, void* d_ws, size_t ws_size,
                              hipStream_t stream) {
  const float* x      = (const float*)d_in[0];
  const float* qkv_w  = (const float*)d_in[1];
  const float* qkv_b  = (const float*)d_in[2];
  const float* proj_w = (const float*)d_in[3];
  const float* proj_b = (const float*)d_in[4];
  float* out = (float*)d_out;
  (void)in_sizes; (void)n_in; (void)out_size; (void)ws_size;

  // workspace layout (~159 MB; attb aliases xb which is dead after QKV GEMM)
  char* ws = (char*)d_ws;
  size_t off = 0;
  auto alloc = [&](size_t bytes) -> void* {
    void* p = (void*)(ws + off);
    off += (bytes + 255) & ~(size_t)255;
    return p;
  };
  const size_t MB0 = (size_t)25088 * 768 * 2;  // 38,535,168 B
  __hip_bfloat16* xb   = (__hip_bfloat16*)alloc(MB0);
  __hip_bfloat16* w1b  = (__hip_bfloat16*)alloc((size_t)2304 * 768 * 2);
  __hip_bfloat16* w2b  = (__hip_bfloat16*)alloc((size_t)768 * 768 * 2);
  float* cosT          = (float*)alloc(196 * 64 * 4);
  float* sinT          = (float*)alloc(196 * 64 * 4);
  __hip_bfloat16* qbuf = (__hip_bfloat16*)alloc(MB0);
  __hip_bfloat16* kbuf = (__hip_bfloat16*)alloc(MB0);
  __hip_bfloat16* vbuf = (__hip_bfloat16*)alloc(MB0);
  __hip_bfloat16* attb = xb;  // alias: xb dead after gemm_qkv

  // prep index space: 4,816,896 + 442,368 + 147,456 float4-casts + 12,544 rope
  // = 5,419,264 threads = 21,169 blocks x 256 (exact).
  prep_kernel<<<21169, 256, 0, stream>>>(x, qkv_w, proj_w, xb, w1b, w2b, cosT, sinT);
  gemm_qkv_kernel<<<3528, 256, 0, stream>>>(xb, w1b, qkv_b, cosT, sinT,
                                            qbuf, kbuf, vbuf);
  attn_kernel<<<1536, 256, 0, stream>>>(qbuf, kbuf, vbuf, attb);
  gemm_proj_kernel<<<1176, 256, 0, stream>>>(attb, w2b, proj_b, out);
}

// Round 6
// 347.333 us; speedup vs baseline: 1.3083x; 1.1436x over previous
//
#include <hip/hip_runtime.h>
#include <hip/hip_bf16.h>

typedef __attribute__((ext_vector_type(8))) short short8;
typedef __attribute__((ext_vector_type(4))) float f32x4;

#define GLD16(gp, lp) \
  __builtin_amdgcn_global_load_lds((const __attribute__((address_space(1))) void*)(gp), \
                                   (__attribute__((address_space(3))) void*)(lp), 16, 0, 0)

__device__ __forceinline__ f32x4 mfma_bf16(short8 a, short8 b, f32x4 c) {
  return __builtin_amdgcn_mfma_f32_16x16x32_bf16(a, b, c, 0, 0, 0);
}

// ---------------- fused prep: cast x/qkv_w/proj_w -> bf16, RoPE table ----------------
__global__ __launch_bounds__(256) void prep_kernel(
    const float* __restrict__ x, const float* __restrict__ qkv_w,
    const float* __restrict__ proj_w, __hip_bfloat16* __restrict__ xb,
    __hip_bfloat16* __restrict__ w1b, __hip_bfloat16* __restrict__ w2b,
    float* __restrict__ cosT, float* __restrict__ sinT) {
  const int N1 = 25088 * 768 / 4;          // 4,816,896
  const int N2 = 2304 * 768 / 4;           // 442,368
  const int N3 = 768 * 768 / 4;            // 147,456
  int i = blockIdx.x * 256 + threadIdx.x;
  const float* src;
  __hip_bfloat16* dst;
  int idx;
  if (i < N1) {
    src = x; dst = xb; idx = i;
  } else if (i < N1 + N2) {
    src = qkv_w; dst = w1b; idx = i - N1;
  } else if (i < N1 + N2 + N3) {
    src = proj_w; dst = w2b; idx = i - N1 - N2;
  } else {
    int r = i - (N1 + N2 + N3);
    if (r < 196 * 64) {
      int t = r >> 6, d = r & 63;
      int c = d & 31;                       // emb = concat([e,e]) over 32
      float pos = (c < 16) ? (float)(t / 14) : (float)(t % 14);  // h then w
      int j = c & 15;                       // freq index
      float invf = expf(-(float)j * 0.5756462732485114f);  // 10000^(-j/16)
      float ang = pos * invf;
      cosT[r] = cosf(ang);
      sinT[r] = sinf(ang);
    }
    return;
  }
  float4 v = reinterpret_cast<const float4*>(src)[idx];
  ushort4 o;
  o.x = __builtin_bit_cast(unsigned short, __float2bfloat16(v.x));
  o.y = __builtin_bit_cast(unsigned short, __float2bfloat16(v.y));
  o.z = __builtin_bit_cast(unsigned short, __float2bfloat16(v.z));
  o.w = __builtin_bit_cast(unsigned short, __float2bfloat16(v.w));
  reinterpret_cast<ushort4*>(dst)[idx] = o;
}

// ---------------- QKV GEMM: [25088x768] x [2304x768]^T + bias, fused RoPE,
//                  scatter to q/k/v [128][12][196][64] bf16 ----------------
// m97-structure, BK=64, XOR chunk-swizzle. Measured plateau ~118 us, 33% MfmaUtil.
// R6: T1 bijective XCD swizzle. The 18 blocks sharing an A-panel are
// consecutive ids; round-robin dispatch (bid%8 -> XCD) spreads them over 8
// non-coherent L2s -> A re-fetched ~8x (FETCH 192 MB vs ~42 ideal). Swizzle
// id=(bid&7)*441+(bid>>3) (3528=8*441, bijective) gives each XCD a contiguous
// id range, so A-panel sharers co-locate on one XCD: FETCH should drop to
// ~70-90 MB AND the 12 per-block vmcnt drains hit L2 (~200cy) not HBM (~900cy).
__global__ __launch_bounds__(256) void gemm_qkv_kernel(
    const __hip_bfloat16* __restrict__ A, const __hip_bfloat16* __restrict__ W,
    const float* __restrict__ bias, const float* __restrict__ cosT,
    const float* __restrict__ sinT, __hip_bfloat16* __restrict__ qb,
    __hip_bfloat16* __restrict__ kb, __hip_bfloat16* __restrict__ vb) {
  __shared__ __align__(16) __hip_bfloat16 As[128 * 64];
  __shared__ __align__(16) __hip_bfloat16 Bs[128 * 64];
  const int tid = threadIdx.x;
  const int bid = blockIdx.x;
  const int id = (bid & 7) * 441 + (bid >> 3);  // XCD-contiguous (3528 = 8*441)
  const int sup = id / 72, rem = id % 72;   // supertile = 4 bm x 18 bn
  const int bm = sup * 4 + rem / 18;
  const int bn = rem % 18;
  const int lane = tid & 63, wv = tid >> 6;
  const int wm = wv >> 1, wn = wv & 1;
  const int quad = lane >> 4, ln = lane & 15;

  const int r0 = tid >> 3;
  const int csw = ((tid & 7) ^ (r0 & 7)) * 8;
  const __hip_bfloat16* Ag = A + ((long)(bm * 128 + r0) * 768 + csw);
  const __hip_bfloat16* Wg = W + ((long)(bn * 128 + r0) * 768 + csw);
  __hip_bfloat16* As0 = As + tid * 8;
  __hip_bfloat16* Bs0 = Bs + tid * 8;

  const int c0 = (quad ^ (ln & 7)) * 8;
  const int c1 = c0 ^ 32;

  f32x4 acc[4][4];
#pragma unroll
  for (int i = 0; i < 4; i++)
#pragma unroll
    for (int j = 0; j < 4; j++) acc[i][j] = (f32x4){0.f, 0.f, 0.f, 0.f};

  for (int k0 = 0; k0 < 768; k0 += 64) {
    GLD16(Ag + k0,            As0);
    GLD16(Ag + 32 * 768 + k0, As0 + 2048);
    GLD16(Ag + 64 * 768 + k0, As0 + 4096);
    GLD16(Ag + 96 * 768 + k0, As0 + 6144);
    GLD16(Wg + k0,            Bs0);
    GLD16(Wg + 32 * 768 + k0, Bs0 + 2048);
    GLD16(Wg + 64 * 768 + k0, Bs0 + 4096);
    GLD16(Wg + 96 * 768 + k0, Bs0 + 6144);
    __syncthreads();
#pragma unroll
    for (int kk = 0; kk < 2; kk++) {
      const int cc = kk ? c1 : c0;
      short8 af[4], bf[4];
#pragma unroll
      for (int i = 0; i < 4; i++)
        af[i] = *(const short8*)(As + (wm * 64 + i * 16 + ln) * 64 + cc);
#pragma unroll
      for (int j = 0; j < 4; j++)
        bf[j] = *(const short8*)(Bs + (wn * 64 + j * 16 + ln) * 64 + cc);
#pragma unroll
      for (int i = 0; i < 4; i++)
#pragma unroll
        for (int j = 0; j < 4; j++) acc[i][j] = mfma_bf16(af[i], bf[j], acc[i][j]);
    }
    __syncthreads();
  }

  const int ncolbase = bn * 128 + wn * 64;  // multiple of 64
  const int s = ncolbase / 768;             // 0=q 1=k 2=v (wave-uniform)
  const int hh = (ncolbase % 768) >> 6;     // head (wave-uniform)
  __hip_bfloat16* outb = (s == 0) ? qb : ((s == 1) ? kb : vb);
  float bi[4];
#pragma unroll
  for (int j = 0; j < 4; j++) bi[j] = bias[ncolbase + j * 16 + ln];
  const bool dorope = (s < 2);

#pragma unroll
  for (int i = 0; i < 4; i++) {
#pragma unroll
    for (int r = 0; r < 4; r++) {
      int m = bm * 128 + wm * 64 + i * 16 + quad * 4 + r;  // row (C layout: quad*4+reg)
      int b = m / 196, t = m - b * 196;
      float v0 = acc[i][0][r] + bi[0];
      float v1 = acc[i][1][r] + bi[1];
      float v2 = acc[i][2][r] + bi[2];
      float v3 = acc[i][3][r] + bi[3];
      if (dorope) {
        const float* ct = cosT + t * 64 + ln;
        const float* st = sinT + t * 64 + ln;
        float c0f = ct[0], c1f = ct[16], c2f = ct[32], c3f = ct[48];
        float s0 = st[0], s1 = st[16], s2 = st[32], s3 = st[48];
        float w0 = v0 * c0f - v2 * s0;   // d<32: rh = -x[d+32]
        float w1 = v1 * c1f - v3 * s1;
        float w2 = v2 * c2f + v0 * s2;   // d>=32: rh = +x[d-32]
        float w3 = v3 * c3f + v1 * s3;
        v0 = w0; v1 = w1; v2 = w2; v3 = w3;
      }
      __hip_bfloat16* op = outb + ((long)(b * 12 + hh) * 196 + t) * 64 + ln;
      op[0]  = __float2bfloat16(v0);
      op[16] = __float2bfloat16(v1);
      op[32] = __float2bfloat16(v2);
      op[48] = __float2bfloat16(v3);
    }
  }
}

// ---------------- attention: one block per (b,h), 4 waves ----------------
// RESTORED to the R0-measured-best dataflow (bulk P tile + tight PV loop).
// R5 post-mortem: the chunked exp->LDS->MFMA variant (4 blocks/CU) ran ~86 us
// vs ~70 us for this form -- the per-32-key fences serialized what this
// version's single P-write phase + clean 28-MFMA PV loop overlap via ILP.
// Occupancy here is 2 blocks/CU (LDS 59.4 KB) and that is the better trade.
__global__ __launch_bounds__(256) void attn_kernel(
    const __hip_bfloat16* __restrict__ qb, const __hip_bfloat16* __restrict__ kb,
    const __hip_bfloat16* __restrict__ vb, __hip_bfloat16* __restrict__ att) {
  __shared__ __align__(16) __hip_bfloat16 Vt[64 * 232];      // V^T [d][key], keys padded to 224
  __shared__ __align__(16) __hip_bfloat16 Ps[4][16 * 232];   // per-wave P tile
  const int bh = blockIdx.x;
  const int b = bh / 12, h = bh - b * 12;
  const int tid = threadIdx.x;
  const int lane = tid & 63, wv = tid >> 6;
  const int quad = lane >> 4, ln = lane & 15;
  const __hip_bfloat16* qg = qb + (long)bh * (196 * 64);
  const __hip_bfloat16* kg = kb + (long)bh * (196 * 64);
  const __hip_bfloat16* vg = vb + (long)bh * (196 * 64);

  // stage V transposed (zero-pad keys 196..223)
  for (int ch = tid; ch < 224 * 8; ch += 256) {
    int row = ch >> 3, c = (ch & 7) * 8;
    unsigned short vals[8] = {0, 0, 0, 0, 0, 0, 0, 0};
    if (row < 196) *(uint4*)vals = *(const uint4*)(vg + row * 64 + c);
#pragma unroll
    for (int u = 0; u < 8; u++)
      ((unsigned short*)Vt)[(c + u) * 232 + row] = vals[u];
  }

  __hip_bfloat16* Pw = &Ps[wv][0];
  // zero pad cols 208..223 once (main loop only writes cols 0..207)
#pragma unroll
  for (int r = 0; r < 4; r++)
    Pw[(quad * 4 + r) * 232 + 208 + ln] = __float2bfloat16(0.f);
  __syncthreads();

  for (int qt = wv; qt < 13; qt += 4) {
    int tok = qt * 16 + ln;
    if (tok > 195) tok = 195;              // clamped rows masked at store
    short8 aq0 = *(const short8*)(qg + tok * 64 + quad * 8);
    short8 aq1 = *(const short8*)(qg + tok * 64 + 32 + quad * 8);

    f32x4 sacc[13];
#pragma unroll
    for (int ct = 0; ct < 13; ct++) {
      int krow = ct * 16 + ln;
      if (krow > 195) krow = 195;          // garbage cols zeroed below
      const __hip_bfloat16* kp = kg + krow * 64 + quad * 8;
      short8 b0 = *(const short8*)kp;
      short8 b1 = *(const short8*)(kp + 32);
      f32x4 cacc = (f32x4){0.f, 0.f, 0.f, 0.f};
      cacc = mfma_bf16(aq0, b0, cacc);
      cacc = mfma_bf16(aq1, b1, cacc);
      sacc[ct] = cacc;
    }

    // no-max softmax: p = exp(s/8), invalid cols -> 0
    float sm[4] = {0.f, 0.f, 0.f, 0.f};
#pragma unroll
    for (int ct = 0; ct < 13; ct++) {
      bool valid = (ct * 16 + ln) < 196;
#pragma unroll
      for (int r = 0; r < 4; r++) {
        float p = valid ? __expf(sacc[ct][r] * 0.125f) : 0.f;
        sm[r] += p;
        Pw[(quad * 4 + r) * 232 + ct * 16 + ln] = __float2bfloat16(p);
      }
    }
#pragma unroll
    for (int mk = 1; mk < 16; mk <<= 1) {
#pragma unroll
      for (int r = 0; r < 4; r++) sm[r] += __shfl_xor(sm[r], mk, 64);
    }
    asm volatile("" ::: "memory");  // order P stores vs short8 reloads (TBAA guard)

    f32x4 o[4];
#pragma unroll
    for (int j = 0; j < 4; j++) o[j] = (f32x4){0.f, 0.f, 0.f, 0.f};
#pragma unroll
    for (int kt = 0; kt < 7; kt++) {
      short8 pa = *(const short8*)(Pw + ln * 232 + kt * 32 + quad * 8);
#pragma unroll
      for (int j = 0; j < 4; j++) {
        short8 bv = *(const short8*)(Vt + (j * 16 + ln) * 232 + kt * 32 + quad * 8);
        o[j] = mfma_bf16(pa, bv, o[j]);
      }
    }
    asm volatile("" ::: "memory");

    float rl[4];
#pragma unroll
    for (int r = 0; r < 4; r++) rl[r] = 1.0f / sm[r];
    int trow = qt * 16 + quad * 4;
#pragma unroll
    for (int r = 0; r < 4; r++) {
      int t = trow + r;
      if (t < 196) {
        __hip_bfloat16* op = att + (long)(b * 196 + t) * 768 + h * 64 + ln;
#pragma unroll
        for (int j = 0; j < 4; j++) op[j * 16] = __float2bfloat16(o[j][r] * rl[r]);
      }
    }
  }
}

// ---------------- proj GEMM: [25088x768] x [768x768]^T + bias -> fp32 out ----------------
// BK=64 + XOR chunk-swizzle (see gemm_qkv). R6: same XCD swizzle (1176 = 8*147).
__global__ __launch_bounds__(256) void gemm_proj_kernel(
    const __hip_bfloat16* __restrict__ A, const __hip_bfloat16* __restrict__ W,
    const float* __restrict__ bias, float* __restrict__ out) {
  __shared__ __align__(16) __hip_bfloat16 As[128 * 64];
  __shared__ __align__(16) __hip_bfloat16 Bs[128 * 64];
  const int tid = threadIdx.x;
  const int bid = blockIdx.x;
  const int id = (bid & 7) * 147 + (bid >> 3);  // XCD-contiguous (1176 = 8*147)
  const int sup = id / 24, rem = id % 24;   // supertile = 4 bm x 6 bn
  const int bm = sup * 4 + rem / 6;
  const int bn = rem % 6;
  const int lane = tid & 63, wv = tid >> 6;
  const int wm = wv >> 1, wn = wv & 1;
  const int quad = lane >> 4, ln = lane & 15;

  const int r0 = tid >> 3;
  const int csw = ((tid & 7) ^ (r0 & 7)) * 8;
  const __hip_bfloat16* Ag = A + ((long)(bm * 128 + r0) * 768 + csw);
  const __hip_bfloat16* Wg = W + ((long)(bn * 128 + r0) * 768 + csw);
  __hip_bfloat16* As0 = As + tid * 8;
  __hip_bfloat16* Bs0 = Bs + tid * 8;

  const int c0 = (quad ^ (ln & 7)) * 8;
  const int c1 = c0 ^ 32;

  f32x4 acc[4][4];
#pragma unroll
  for (int i = 0; i < 4; i++)
#pragma unroll
    for (int j = 0; j < 4; j++) acc[i][j] = (f32x4){0.f, 0.f, 0.f, 0.f};

  for (int k0 = 0; k0 < 768; k0 += 64) {
    GLD16(Ag + k0,            As0);
    GLD16(Ag + 32 * 768 + k0, As0 + 2048);
    GLD16(Ag + 64 * 768 + k0, As0 + 4096);
    GLD16(Ag + 96 * 768 + k0, As0 + 6144);
    GLD16(Wg + k0,            Bs0);
    GLD16(Wg + 32 * 768 + k0, Bs0 + 2048);
    GLD16(Wg + 64 * 768 + k0, Bs0 + 4096);
    GLD16(Wg + 96 * 768 + k0, Bs0 + 6144);
    __syncthreads();
#pragma unroll
    for (int kk = 0; kk < 2; kk++) {
      const int cc = kk ? c1 : c0;
      short8 af[4], bf[4];
#pragma unroll
      for (int i = 0; i < 4; i++)
        af[i] = *(const short8*)(As + (wm * 64 + i * 16 + ln) * 64 + cc);
#pragma unroll
      for (int j = 0; j < 4; j++)
        bf[j] = *(const short8*)(Bs + (wn * 64 + j * 16 + ln) * 64 + cc);
#pragma unroll
      for (int i = 0; i < 4; i++)
#pragma unroll
        for (int j = 0; j < 4; j++) acc[i][j] = mfma_bf16(af[i], bf[j], acc[i][j]);
    }
    __syncthreads();
  }

  const int ncolbase = bn * 128 + wn * 64;
  float bi[4];
#pragma unroll
  for (int j = 0; j < 4; j++) bi[j] = bias[ncolbase + j * 16 + ln];
#pragma unroll
  for (int i = 0; i < 4; i++) {
#pragma unroll
    for (int r = 0; r < 4; r++) {
      int m = bm * 128 + wm * 64 + i * 16 + quad * 4 + r;
      float* op = out + (long)m * 768 + ncolbase + ln;
      op[0]  = acc[i][0][r] + bi[0];
      op[16] = acc[i][1][r] + bi[1];
      op[32] = acc[i][2][r] + bi[2];
      op[48] = acc[i][3][r] + bi[3];
    }
  }
}

extern "C" void kernel_launch(void* const* d_in, const int* in_sizes, int n_in,
                              void* d_out, int out_size, void* d_ws, size_t ws_size,
                              hipStream_t stream) {
  const float* x      = (const float*)d_in[0];
  const float* qkv_w  = (const float*)d_in[1];
  const float* qkv_b  = (const float*)d_in[2];
  const float* proj_w = (const float*)d_in[3];
  const float* proj_b = (const float*)d_in[4];
  float* out = (float*)d_out;
  (void)in_sizes; (void)n_in; (void)out_size; (void)ws_size;

  // workspace layout (~159 MB; attb aliases xb which is dead after QKV GEMM)
  char* ws = (char*)d_ws;
  size_t off = 0;
  auto alloc = [&](size_t bytes) -> void* {
    void* p = (void*)(ws + off);
    off += (bytes + 255) & ~(size_t)255;
    return p;
  };
  const size_t MB0 = (size_t)25088 * 768 * 2;  // 38,535,168 B
  __hip_bfloat16* xb   = (__hip_bfloat16*)alloc(MB0);
  __hip_bfloat16* w1b  = (__hip_bfloat16*)alloc((size_t)2304 * 768 * 2);
  __hip_bfloat16* w2b  = (__hip_bfloat16*)alloc((size_t)768 * 768 * 2);
  float* cosT          = (float*)alloc(196 * 64 * 4);
  float* sinT          = (float*)alloc(196 * 64 * 4);
  __hip_bfloat16* qbuf = (__hip_bfloat16*)alloc(MB0);
  __hip_bfloat16* kbuf = (__hip_bfloat16*)alloc(MB0);
  __hip_bfloat16* vbuf = (__hip_bfloat16*)alloc(MB0);
  __hip_bfloat16* attb = xb;  // alias: xb dead after gemm_qkv

  // prep index space: 4,816,896 + 442,368 + 147,456 float4-casts + 12,544 rope
  // = 5,419,264 threads = 21,169 blocks x 256 (exact).
  prep_kernel<<<21169, 256, 0, stream>>>(x, qkv_w, proj_w, xb, w1b, w2b, cosT, sinT);
  gemm_qkv_kernel<<<3528, 256, 0, stream>>>(xb, w1b, qkv_b, cosT, sinT,
                                            qbuf, kbuf, vbuf);
  attn_kernel<<<1536, 256, 0, stream>>>(qbuf, kbuf, vbuf, attb);
  gemm_proj_kernel<<<1176, 256, 0, stream>>>(attb, w2b, proj_b, out);
}